// Round 12
// baseline (481.667 us; speedup 1.0000x reference)
//
#include <hip/hip_runtime.h>

#define E_EDGES   1000000
#define NNODES    2048
#define HCH       128
#define KP        136            // w1t row stride bf16: 128 z + 4 attrW + bias + 3 zero
#define TILE      64
#define NTILES    (E_EDGES / TILE)   // 15625 exact
#define NSPREAD   8
#define GRID_GEMM 1024           // 4 blocks/CU; bid%8 -> XCD (round-robin dispatch)
#define BPB       128            // blocks per bin (GRID_GEMM/8)
#define ZVEC      (32 * 2048 * 64 / 4)
#define ZBLK      2048
#define WBLK      66             // 66*256 = 132*128 w1t transpose elements
#define NBIN      8              // bins by src>>13: 1 MB of zb each (fits XCD L2)
#define CBLK      512            // count/scatter blocks

typedef short  shortx8 __attribute__((ext_vector_type(8)));
typedef float  floatx4 __attribute__((ext_vector_type(4)));

__device__ __forceinline__ unsigned short f2bf(float f) {
  union { float f; unsigned int u; } v; v.f = f;
  unsigned int r = (v.u + 0x7fffu + ((v.u >> 16) & 1u)) >> 16;
  return (unsigned short)r;
}
__device__ __forceinline__ unsigned pack_rows(int s, int d) {
  unsigned rs = (unsigned)s & 0xFFFFu;
  unsigned rd = (unsigned)(((s & ~(NNODES - 1)) | (d & (NNODES - 1)))) & 0xFFFFu;
  return rs | (rd << 16);
}

// ---------------------------------------------------------------- prep ----
// zb cast, w1t transpose, gstats zero, out zero (atomic combine), histogram.
__global__ void k_prep(const float* __restrict__ z, const float* __restrict__ W1,
                       const float* __restrict__ b1, const int* __restrict__ ei,
                       unsigned short* __restrict__ zb, unsigned short* __restrict__ w1t,
                       float* __restrict__ gstats, int* __restrict__ cnt,
                       float* __restrict__ out) {
  int bid = blockIdx.x;
  if (bid < ZBLK) {
    const float4* z4 = (const float4*)z;
    ushort4* zb4 = (ushort4*)zb;
    for (int i = bid * 256 + threadIdx.x; i < ZVEC; i += ZBLK * 256) {
      float4 v = z4[i];
      ushort4 o;
      o.x = f2bf(v.x); o.y = f2bf(v.y); o.z = f2bf(v.z); o.w = f2bf(v.w);
      zb4[i] = o;
    }
    float4 zf = {0.f, 0.f, 0.f, 0.f};
    float4* o4 = (float4*)out;
    for (int i = bid * 256 + threadIdx.x; i < (E_EDGES / 4); i += ZBLK * 256) o4[i] = zf;
  } else if (bid < ZBLK + WBLK) {
    int idx = (bid - ZBLK) * 256 + threadIdx.x;   // 0..16895 = 132*128
    int k = idx >> 7, n = idx & 127;              // coalesced read of W1
    w1t[n * KP + k] = f2bf(W1[idx]);
  } else if (bid == ZBLK + WBLK) {
    int tid = threadIdx.x;
    if (tid < 512) {   // pad k=132..135: bias at 132, zeros after
      int n = tid >> 2, kp = 132 + (tid & 3);
      w1t[n * KP + kp] = (kp == 132) ? f2bf(b1[n]) : (unsigned short)0;
    }
    for (int i = tid; i < NSPREAD * 2 * HCH; i += 256) gstats[i] = 0.f;
  } else {
    __shared__ int lh[NBIN];
    int tid = threadIdx.x;
    int cb = bid - (ZBLK + WBLK + 1);
    if (tid < NBIN) lh[tid] = 0;
    __syncthreads();
    for (int e = cb * 256 + tid; e < E_EDGES; e += CBLK * 256)
      atomicAdd(&lh[((unsigned)ei[e]) >> 13], 1);
    __syncthreads();
    if (tid < NBIN) cnt[cb * NBIN + tid] = lh[tid];
  }
}

// ---------------------------------------------------------------- scan ----
__global__ void k_scan(const int* __restrict__ cnt, int* __restrict__ base,
                       int* __restrict__ binTile) {
  __shared__ int tot[NBIN], S[NBIN + 1];
  int b = threadIdx.x;
  if (b < NBIN) {
    int t = 0;
    for (int blk = 0; blk < CBLK; ++blk) t += cnt[blk * NBIN + b];
    tot[b] = t;
  }
  __syncthreads();
  if (b == 0) {
    int a = 0;
    for (int i = 0; i < NBIN; ++i) { S[i] = a; a += tot[i]; }
    S[NBIN] = a;
    binTile[0] = 0;
    for (int i = 1; i <= NBIN; ++i) binTile[i] = (S[i] + 63) >> 6;  // [NBIN]=15625
  }
  __syncthreads();
  if (b < NBIN) {
    int run = S[b];
    for (int blk = 0; blk < CBLK; ++blk) {
      base[blk * NBIN + b] = run;
      run += cnt[blk * NBIN + b];
    }
  }
}

// ------------------------------------------------------------- scatter ----
__global__ __launch_bounds__(256)
void k_scatter(const int* __restrict__ ei, const float* __restrict__ attr,
               const int* __restrict__ base, uint4* __restrict__ recs) {
  __shared__ int lcnt[NBIN];
  int tid = threadIdx.x, bid = blockIdx.x;
  if (tid < NBIN) lcnt[tid] = base[bid * NBIN + tid];
  __syncthreads();
  for (int e = bid * 256 + tid; e < E_EDGES; e += CBLK * 256) {
    int s = ei[e], d = ei[E_EDGES + e];
    float4 a = ((const float4*)attr)[e];
    int b = ((unsigned)s) >> 13;
    int slot = atomicAdd(&lcnt[b], 1);
    uint4 r;
    r.x = pack_rows(s, d);
    r.y = (unsigned)f2bf(a.x) | ((unsigned)f2bf(a.y) << 16);
    r.z = (unsigned)f2bf(a.z) | ((unsigned)f2bf(a.w) << 16);
    r.w = (unsigned)e;
    recs[slot] = r;
  }
}

// ---------------------------------------------------------------- gemm ----
// ZERO-LDS, ZERO-BARRIER tile machine. MFMA A-fragments load DIRECTLY from
// global: for 16x16x32, lane (l15,quad) needs a[e=l15][k=quad*8+kk*32..] =
// the 16B of zb row[e] at byte offset kk*64+quad*16 — exactly one ldx4.
// Waves are fully independent (channel quarter w each; the 4 waves' identical
// A-loads dedup in L1; bucketing keeps each XCD's gather slice L2-resident).
// OUT combine: atomicAdd to pre-zeroed out[orig] (4 partials/edge, w0 adds b2).
template<bool OUT>
__global__ __launch_bounds__(256, 4)
void k_gemm(const unsigned short* __restrict__ zb,
            const unsigned short* __restrict__ w1t,
            const uint4* __restrict__ recs,
            const int* __restrict__ binTile,
            float* __restrict__ gstats,
            const float* __restrict__ gamma,
            const float* __restrict__ beta,
            const float* __restrict__ W2,
            const float* __restrict__ b2,
            float* __restrict__ out) {
  const int tid  = threadIdx.x;
  const int lane = tid & 63;
  const int w    = tid >> 6;      // channel quarter
  const int l15  = lane & 15;
  const int quad = lane >> 4;

  // ---- B fragments: 2 n-tiles x 5 k-steps for this wave's 32 channels
  shortx8 bfr[2][4], bfr4[2];
#pragma unroll
  for (int nt = 0; nt < 2; ++nt) {
    const unsigned short* bp = w1t + (w * 32 + nt * 16 + l15) * KP;
#pragma unroll
    for (int kk = 0; kk < 4; ++kk)
      bfr[nt][kk] = *(const shortx8*)(bp + kk * 32 + quad * 8);
    bfr4[nt] = (quad == 0) ? *(const shortx8*)(bp + 128)
                           : (shortx8){0, 0, 0, 0, 0, 0, 0, 0};
  }

  float eaf[2], ebb[2], ew2[2], b2v = 0.f;
  float ssum[2] = {0.f, 0.f}, ssq[2] = {0.f, 0.f};
  if (OUT) {
#pragma unroll
    for (int nt = 0; nt < 2; ++nt) {
      int c = w * 32 + nt * 16 + l15;
      float S = 0.f, Q = 0.f;
#pragma unroll
      for (int i = 0; i < NSPREAD; ++i) {
        S += gstats[i * 2 * HCH + c];
        Q += gstats[i * 2 * HCH + HCH + c];
      }
      float mu   = S * (1.0f / (float)E_EDGES);
      float var  = Q * (1.0f / (float)E_EDGES) - mu * mu;
      float rstd = rsqrtf(var + 1e-5f);
      float a = gamma[c] * rstd;
      eaf[nt] = a;
      ebb[nt] = beta[c] - mu * a;
      ew2[nt] = W2[c];
    }
    b2v = (w == 0) ? b2[0] : 0.f;   // b2 added once per edge (by wave 0)
  }

  // ---- bin-pinned tile range
  const int x    = blockIdx.x & 7;               // bin == XCD
  const int t0i  = binTile[x] + (blockIdx.x >> 3);
  const int tEnd = binTile[x + 1];
  if (t0i >= tEnd) return;

  const char* zq = (const char*)zb + quad * 16;   // fold quad offset into base

  // load the 4 direct A-fragments (one mt) given a rec
  auto zload = [&](uint4 rec, uint4* zf) {
    unsigned so = (rec.x & 0xFFFFu) << 7;   // src row byte offset
    unsigned dofs = (rec.x >> 16) << 7;     // dst row byte offset
    zf[0] = *(const uint4*)(zq + so);
    zf[1] = *(const uint4*)(zq + so + 64);
    zf[2] = *(const uint4*)(zq + dofs);
    zf[3] = *(const uint4*)(zq + dofs + 64);
  };

  // MFMA + epilogue for one m-tile
  auto do_mt = [&](uint4 rec, const uint4* zf, int tile, int mt) {
    int4 ai;
    if (quad == 0) { ai.x = (int)rec.y; ai.y = (int)rec.z; ai.z = 0x3F80; ai.w = 0; }
    else           { ai.x = 0; ai.y = 0; ai.z = 0; ai.w = 0; }
    shortx8 a4; __builtin_memcpy(&a4, &ai, 16);

    floatx4 acc[2];
    acc[0] = (floatx4){0.f, 0.f, 0.f, 0.f};
    acc[1] = (floatx4){0.f, 0.f, 0.f, 0.f};
#pragma unroll
    for (int kk = 0; kk < 4; ++kk) {
      shortx8 afr; __builtin_memcpy(&afr, &zf[kk], 16);
#pragma unroll
      for (int nt = 0; nt < 2; ++nt)
        acc[nt] = __builtin_amdgcn_mfma_f32_16x16x32_bf16(
            afr, bfr[nt][kk], acc[nt], 0, 0, 0);
    }
#pragma unroll
    for (int nt = 0; nt < 2; ++nt)
      acc[nt] = __builtin_amdgcn_mfma_f32_16x16x32_bf16(
          a4, bfr4[nt], acc[nt], 0, 0, 0);

    // C/D: col=l15 (channel), row=quad*4+r (edge within m-tile)
    if (!OUT) {
#pragma unroll
      for (int nt = 0; nt < 2; ++nt) {
        float s = 0.f, qq = 0.f;
#pragma unroll
        for (int r = 0; r < 4; ++r) {
          float h = acc[nt][r];
          s += h; qq += h * h;
        }
        ssum[nt] += s; ssq[nt] += qq;
      }
    } else {
#pragma unroll
      for (int r = 0; r < 4; ++r) {
        float t = 0.f;
#pragma unroll
        for (int nt = 0; nt < 2; ++nt) {
          float h = acc[nt][r];
          float p = fmaf(eaf[nt], h, ebb[nt]);
          p = fmaxf(p, 0.2f * p);             // LeakyReLU(0.2)
          t = fmaf(ew2[nt], p, t);
        }
        t += __shfl_xor(t, 1);
        t += __shfl_xor(t, 2);
        t += __shfl_xor(t, 4);
        t += __shfl_xor(t, 8);   // sum over this wave's 32 channels
        int og = __shfl((int)rec.w, quad * 4 + r);  // orig idx of edge quad*4+r
        if (l15 == 0) atomicAdd(&out[og], t + b2v);
      }
    }
  };

  for (int tile = t0i; tile < tEnd; tile += BPB) {
    const uint4* rt = recs + tile * TILE + l15;
    uint4 r0 = rt[0], r1 = rt[16], r2 = rt[32], r3 = rt[48];
    uint4 za[4], zc[4];
    zload(r0, za);
    zload(r1, zc);
    do_mt(r0, za, tile, 0);
    zload(r2, za);
    do_mt(r1, zc, tile, 1);
    zload(r3, zc);
    do_mt(r2, za, tile, 2);
    do_mt(r3, zc, tile, 3);
  }

  if (!OUT) {   // quads hold disjoint edge subsets; reduce, one atomic set
    float* gs = gstats + (blockIdx.x & (NSPREAD - 1)) * 2 * HCH;
#pragma unroll
    for (int nt = 0; nt < 2; ++nt) {
      float s = ssum[nt], qq = ssq[nt];
      s += __shfl_xor(s, 16); s += __shfl_xor(s, 32);
      qq += __shfl_xor(qq, 16); qq += __shfl_xor(qq, 32);
      if (quad == 0) {
        int c = w * 32 + nt * 16 + l15;
        atomicAdd(&gs[c], s);
        atomicAdd(&gs[HCH + c], qq);
      }
    }
  }
}

// -------------------------------------------------------------- launch ----
extern "C" void kernel_launch(void* const* d_in, const int* in_sizes, int n_in,
                              void* d_out, int out_size, void* d_ws, size_t ws_size,
                              hipStream_t stream) {
  const float* z     = (const float*)d_in[0];
  const float* attr  = (const float*)d_in[1];
  const float* W1    = (const float*)d_in[2];
  const float* b1    = (const float*)d_in[3];
  const float* gamma = (const float*)d_in[4];
  const float* beta  = (const float*)d_in[5];
  const float* W2    = (const float*)d_in[6];
  const float* b2    = (const float*)d_in[7];
  const int*   ei    = (const int*)d_in[8];
  float* out = (float*)d_out;

  char* ws = (char*)d_ws;
  unsigned short* zb  = (unsigned short*)ws;                 //  8,388,608 B
  unsigned short* w1t = (unsigned short*)(ws + 8388608);     //     34,816 B
  float* gstats       = (float*)(ws + 8423424);              //      8,192 B
  int* cnt            = (int*)(ws + 8431616);                //     16,384 B
  int* base           = (int*)(ws + 8448000);                //     16,384 B
  int* binTile        = (int*)(ws + 8464384);                //         64 B
  uint4* recs         = (uint4*)(ws + 8464448);              // 16,000,000 B

  k_prep<<<ZBLK + WBLK + 1 + CBLK, 256, 0, stream>>>(z, W1, b1, ei, zb, w1t,
                                                     gstats, cnt, out);
  k_scan<<<1, 64, 0, stream>>>(cnt, base, binTile);
  k_scatter<<<CBLK, 256, 0, stream>>>(ei, attr, base, recs);
  k_gemm<false><<<GRID_GEMM, 256, 0, stream>>>(zb, w1t, recs, binTile, gstats,
                                               gamma, beta, W2, b2, nullptr);
  k_gemm<true><<<GRID_GEMM, 256, 0, stream>>>(zb, w1t, recs, binTile, gstats,
                                              gamma, beta, W2, b2, out);
}